// Round 9
// baseline (689.586 us; speedup 1.0000x reference)
//
#include <hip/hip_runtime.h>
#include <hip/hip_fp16.h>

#define HID 256
#define CH 16          // edge chunks for histogram/placement
#define LDSW 12544     // LDS words per bin-half (supports N/2 up to ~25088 bins)

typedef _Float16 f16x8 __attribute__((ext_vector_type(8)));
typedef float    f32x4 __attribute__((ext_vector_type(4)));

// ---------- fp16 pack/unpack helpers ----------
__device__ inline unsigned int h2_as_u32(__half2 h) {
    union { __half2 h; unsigned int u; } c; c.h = h; return c.u;
}
__device__ inline float4 u2_to_f4(uint2 u) {
    union { unsigned int u; __half2 h; } a, b;
    a.u = u.x; b.u = u.y;
    float2 fa = __half22float2(a.h);
    float2 fb = __half22float2(b.h);
    return make_float4(fa.x, fa.y, fb.x, fb.y);
}

// ---------------- LDS-privatized histogram (no global atomics) ----------------
// grid = CH*2 blocks: c = bid>>1 (edge chunk), h = bid&1 (bin half).
// Packed 16-bit counts in LDS; plain-stores per-(chunk,bin) counts to hist[c*n+bin].
__global__ __launch_bounds__(1024) void k_hist(const int* __restrict__ idx,
                                               unsigned int* __restrict__ hist,
                                               int ne, int n, int chunk) {
    __shared__ unsigned int hl[LDSW];
    int tid = threadIdx.x;
    int c = blockIdx.x >> 1, h = blockIdx.x & 1;
    int nhalf = (n + 1) >> 1;
    int b0 = h * nhalf;
    int b1 = min(n, b0 + nhalf);
    int nw = (b1 - b0 + 1) >> 1;
    for (int i = tid; i < nw; i += 1024) hl[i] = 0;
    __syncthreads();
    int e0 = c * chunk, e1 = min(ne, e0 + chunk);
    for (int e = e0 + tid; e < e1; e += 1024) {
        int b = idx[e];
        if (b >= b0 && b < b1) {
            int l = b - b0;
            atomicAdd(&hl[l >> 1], 1u << ((l & 1) << 4));
        }
    }
    __syncthreads();
    for (int i = tid; i < nw; i += 1024) {
        unsigned int v = hl[i];
        int bin = b0 + (i << 1);
        hist[(size_t)c * n + bin] = v & 0xFFFFu;
        if (bin + 1 < b1) hist[(size_t)c * n + bin + 1] = v >> 16;
    }
}

// ---------------- per-bin: norms + per-chunk placement bases + deg_in ----------------
__global__ void k_bbase_norm(const unsigned int* __restrict__ histO,
                             const unsigned int* __restrict__ histI,
                             int* __restrict__ bb,
                             int* __restrict__ deg_in,
                             float* __restrict__ norm_out,
                             float* __restrict__ norm_in,
                             int n) {
    int bin = blockIdx.x * 256 + threadIdx.x;
    if (bin >= n) return;
    unsigned int dout = 0;
    #pragma unroll
    for (int c = 0; c < CH; c++) dout += histO[(size_t)c * n + bin];
    unsigned int run = 0;
    #pragma unroll
    for (int c = 0; c < CH; c++) {
        bb[(size_t)c * n + bin] = run;
        run += histI[(size_t)c * n + bin];
    }
    deg_in[bin] = run;
    norm_out[bin] = dout > 0 ? 1.0f / sqrtf((float)dout) : 1.0f;
    norm_in[bin]  = run  > 0 ? 1.0f / sqrtf((float)run)  : 1.0f;
}

// ---------------- hierarchical exclusive scan: deg_in -> row_ptr ----------------
__global__ void k_scan_local(const int* __restrict__ deg, int* __restrict__ rp,
                             int* __restrict__ bsum, int n) {
    __shared__ int sd[1024];
    int tid = threadIdx.x;
    int i = blockIdx.x * 1024 + tid;
    int v = (i < n) ? deg[i] : 0;
    sd[tid] = v;
    __syncthreads();
    for (int o = 1; o < 1024; o <<= 1) {
        int t = (tid >= o) ? sd[tid - o] : 0;
        __syncthreads();
        sd[tid] += t;
        __syncthreads();
    }
    if (i < n) rp[i] = sd[tid] - v;           // local exclusive
    if (tid == 1023) bsum[blockIdx.x] = sd[1023];
}

__global__ void k_scan_bsum(int* __restrict__ bsum, int nb) {
    if (threadIdx.x == 0 && blockIdx.x == 0) {
        int run = 0;
        for (int i = 0; i < nb; i++) { int v = bsum[i]; bsum[i] = run; run += v; }
        bsum[nb] = run;
    }
}

__global__ void k_scan_add(int* __restrict__ rp, const int* __restrict__ bsum,
                           int n, int nb) {
    int i = blockIdx.x * 1024 + threadIdx.x;
    if (i < n) rp[i] += bsum[blockIdx.x];
    if (i == 0) rp[n] = bsum[nb];
}

// ---------------- place edges into CSR (LDS cursors, no global atomics) ----------------
__global__ __launch_bounds__(1024) void k_place(const int* __restrict__ src,
                                                const int* __restrict__ dst,
                                                const int* __restrict__ rp,
                                                const int* __restrict__ bb,
                                                int* __restrict__ colx,
                                                int ne, int n, int chunk) {
    __shared__ unsigned int hl[LDSW];
    int tid = threadIdx.x;
    int c = blockIdx.x >> 1, h = blockIdx.x & 1;
    int nhalf = (n + 1) >> 1;
    int b0 = h * nhalf;
    int b1 = min(n, b0 + nhalf);
    int nw = (b1 - b0 + 1) >> 1;
    for (int i = tid; i < nw; i += 1024) hl[i] = 0;
    __syncthreads();
    int e0 = c * chunk, e1 = min(ne, e0 + chunk);
    for (int e = e0 + tid; e < e1; e += 1024) {
        int b = dst[e];
        if (b >= b0 && b < b1) {
            int l = b - b0;
            int sh = (l & 1) << 4;
            unsigned int old = atomicAdd(&hl[l >> 1], 1u << sh);
            int pos = (old >> sh) & 0xFFFF;
            colx[rp[b] + bb[(size_t)c * n + b] + pos] = src[e];
        }
    }
}

// ---------------- W convert+transpose: Wt[n][k] = (fp16) W[k][n] ----------------
__global__ void k_cvtW(const float* __restrict__ W, _Float16* __restrict__ Wt, int K) {
    int n = blockIdx.x;
    int k = threadIdx.x;
    Wt[(size_t)n * K + k] = (_Float16)W[(size_t)k * HID + n];
}

// ---------------- MFMA fp16 GEMM: C = epi(A[M,K] @ W[K,256]) ----------------
// block: 64 rows x 256 cols, 256 threads = 4 waves (2x2), BK=64.
// Wt is pre-transposed fp16 [256][K].
// EPI 0: A fp32; C fp16 = (acc + bias[c]) * scale[row0+r]   (per-type linear)
// EPI 1: A fp16; C fp32 = relu(acc + bias[c])               (final layer)
template <int K, int EPI>
__global__ __launch_bounds__(256) void k_mgemm(const void* __restrict__ Av,
                                               const _Float16* __restrict__ Wt,
                                               const float* __restrict__ bias,
                                               const float* __restrict__ scale,
                                               void* __restrict__ Cv,
                                               int M, int row0) {
    __shared__ _Float16 As[64][72];    // 64 rows x BK=64 (+8 pad: 2-way bank alias only)
    __shared__ _Float16 Bs[256][72];   // 256 cols x BK=64 (+8 pad)
    int t = threadIdx.x, lane = t & 63, wave = t >> 6;
    int wm = wave >> 1, wn = wave & 1;          // 2x2 wave grid
    int rbase = blockIdx.x * 64;
    int cl = lane & 15, kg = lane >> 4;         // fragment col / k-group

    f32x4 zero = {0.f, 0.f, 0.f, 0.f};
    f32x4 acc[2][8];
    #pragma unroll
    for (int i = 0; i < 2; i++)
        #pragma unroll
        for (int j = 0; j < 8; j++) acc[i][j] = zero;

    for (int k0 = 0; k0 < K; k0 += 64) {
        // ---- stage A tile (64 x 64), convert fp32->fp16 if EPI==0 ----
        {
            int r = t >> 2, seg = t & 3;           // each thread: 16 halves of one row
            int gr = rbase + r; if (gr >= M) gr = M - 1;
            if (EPI == 0) {
                const float* A = (const float*)Av;
                const float4* p = (const float4*)(A + (size_t)gr * K + k0 + seg * 16);
                float4 a = p[0], b = p[1], c = p[2], d = p[3];
                f16x8 h0 = {(_Float16)a.x, (_Float16)a.y, (_Float16)a.z, (_Float16)a.w,
                            (_Float16)b.x, (_Float16)b.y, (_Float16)b.z, (_Float16)b.w};
                f16x8 h1 = {(_Float16)c.x, (_Float16)c.y, (_Float16)c.z, (_Float16)c.w,
                            (_Float16)d.x, (_Float16)d.y, (_Float16)d.z, (_Float16)d.w};
                *(f16x8*)&As[r][seg * 16]     = h0;
                *(f16x8*)&As[r][seg * 16 + 8] = h1;
            } else {
                const _Float16* A = (const _Float16*)Av;
                const uint4* p = (const uint4*)(A + (size_t)gr * K + k0 + seg * 16);
                *(uint4*)&As[r][seg * 16]     = p[0];
                *(uint4*)&As[r][seg * 16 + 8] = p[1];
            }
        }
        // ---- stage B tile (256 cols x 64 k) from pre-transposed Wt ----
        {
            const uint4* p = (const uint4*)(Wt + (size_t)t * K + k0);
            #pragma unroll
            for (int j = 0; j < 8; j++) *(uint4*)&Bs[t][j * 8] = p[j];
        }
        __syncthreads();

        // ---- MFMA: wave computes 32 x 128 ----
        f16x8 af[2][2];
        #pragma unroll
        for (int mf = 0; mf < 2; mf++)
            #pragma unroll
            for (int c = 0; c < 2; c++)
                af[mf][c] = *(f16x8*)&As[wm * 32 + mf * 16 + cl][c * 32 + kg * 8];
        #pragma unroll
        for (int nf = 0; nf < 8; nf++) {
            int bn = wn * 128 + nf * 16 + cl;
            f16x8 bf0 = *(f16x8*)&Bs[bn][kg * 8];
            f16x8 bf1 = *(f16x8*)&Bs[bn][32 + kg * 8];
            acc[0][nf] = __builtin_amdgcn_mfma_f32_16x16x32_f16(af[0][0], bf0, acc[0][nf], 0, 0, 0);
            acc[0][nf] = __builtin_amdgcn_mfma_f32_16x16x32_f16(af[0][1], bf1, acc[0][nf], 0, 0, 0);
            acc[1][nf] = __builtin_amdgcn_mfma_f32_16x16x32_f16(af[1][0], bf0, acc[1][nf], 0, 0, 0);
            acc[1][nf] = __builtin_amdgcn_mfma_f32_16x16x32_f16(af[1][1], bf1, acc[1][nf], 0, 0, 0);
        }
        __syncthreads();
    }

    // ---- epilogue: C/D layout col=lane&15, row=(lane>>4)*4+reg ----
    #pragma unroll
    for (int mf = 0; mf < 2; mf++) {
        int lr = wm * 32 + mf * 16 + kg * 4;
        int g0 = rbase + lr;
        float s[4];
        if (EPI == 0) {
            #pragma unroll
            for (int r = 0; r < 4; r++) {
                int gr = g0 + r; if (gr >= M) gr = M - 1;
                s[r] = scale[row0 + gr];
            }
        }
        #pragma unroll
        for (int nf = 0; nf < 8; nf++) {
            int col = wn * 128 + nf * 16 + cl;
            float bb = bias[col];
            #pragma unroll
            for (int r = 0; r < 4; r++) {
                int gr = g0 + r;
                if (gr < M) {
                    float v = acc[mf][nf][r] + bb;
                    if (EPI == 0) {
                        ((_Float16*)Cv)[(size_t)(row0 + gr) * HID + col] = (_Float16)(v * s[r]);
                    } else {
                        ((float*)Cv)[(size_t)gr * HID + col] = fmaxf(v, 0.f);
                    }
                }
            }
        }
    }
}

// ---------------- pull-style SpMM over CSR (fp16 rows); 1 wave per dst node; 8x unrolled ----
// MODE 0: hout(fp16) = relu(acc*norm_in + bias) * norm_out  (layer-0 out, prescaled for layer 1)
// MODE 1: hout(fp16) = acc*norm_in                           (pre-GEMM agg for layer 1)
template <int MODE>
__global__ __launch_bounds__(256) void k_spmm(const __half* __restrict__ hin,
                                              const int* __restrict__ rp,
                                              const int* __restrict__ colx,
                                              const float* __restrict__ norm_in,
                                              const float* __restrict__ norm_out,
                                              const float* __restrict__ bias,
                                              __half* __restrict__ hout,
                                              int n) {
    int node = blockIdx.x * 4 + (threadIdx.x >> 6);
    if (node >= n) return;
    int lane = threadIdx.x & 63;
    int start = rp[node], end = rp[node + 1];
    const __half* hb = hin + lane * 4;   // each lane covers feature cols [lane*4, lane*4+4)

    float4 acc = make_float4(0.f, 0.f, 0.f, 0.f);
    float4 acc2 = make_float4(0.f, 0.f, 0.f, 0.f);
    int j = start;
    for (; j + 8 <= end; j += 8) {
        int s0 = colx[j + 0], s1 = colx[j + 1], s2 = colx[j + 2], s3 = colx[j + 3];
        int s4 = colx[j + 4], s5 = colx[j + 5], s6 = colx[j + 6], s7 = colx[j + 7];
        uint2 u0 = *(const uint2*)(hb + (size_t)s0 * HID);
        uint2 u1 = *(const uint2*)(hb + (size_t)s1 * HID);
        uint2 u2 = *(const uint2*)(hb + (size_t)s2 * HID);
        uint2 u3 = *(const uint2*)(hb + (size_t)s3 * HID);
        uint2 u4 = *(const uint2*)(hb + (size_t)s4 * HID);
        uint2 u5 = *(const uint2*)(hb + (size_t)s5 * HID);
        uint2 u6 = *(const uint2*)(hb + (size_t)s6 * HID);
        uint2 u7 = *(const uint2*)(hb + (size_t)s7 * HID);
        float4 v0 = u2_to_f4(u0), v1 = u2_to_f4(u1), v2 = u2_to_f4(u2), v3 = u2_to_f4(u3);
        float4 v4 = u2_to_f4(u4), v5 = u2_to_f4(u5), v6 = u2_to_f4(u6), v7 = u2_to_f4(u7);
        acc.x += v0.x + v1.x; acc.y += v0.y + v1.y; acc.z += v0.z + v1.z; acc.w += v0.w + v1.w;
        acc2.x += v2.x + v3.x; acc2.y += v2.y + v3.y; acc2.z += v2.z + v3.z; acc2.w += v2.w + v3.w;
        acc.x += v4.x + v5.x; acc.y += v4.y + v5.y; acc.z += v4.z + v5.z; acc.w += v4.w + v5.w;
        acc2.x += v6.x + v7.x; acc2.y += v6.y + v7.y; acc2.z += v6.z + v7.z; acc2.w += v6.w + v7.w;
    }
    for (; j < end; j++) {
        int s = colx[j];
        float4 v = u2_to_f4(*(const uint2*)(hb + (size_t)s * HID));
        acc.x += v.x; acc.y += v.y; acc.z += v.z; acc.w += v.w;
    }
    acc.x += acc2.x; acc.y += acc2.y; acc.z += acc2.z; acc.w += acc2.w;

    float ni = norm_in[node];
    uint2 st;
    if (MODE == 0) {
        float no = norm_out[node];
        float4 bb = *(const float4*)(bias + lane * 4);
        float o0 = fmaxf(acc.x * ni + bb.x, 0.f) * no;
        float o1 = fmaxf(acc.y * ni + bb.y, 0.f) * no;
        float o2 = fmaxf(acc.z * ni + bb.z, 0.f) * no;
        float o3 = fmaxf(acc.w * ni + bb.w, 0.f) * no;
        st.x = h2_as_u32(__floats2half2_rn(o0, o1));
        st.y = h2_as_u32(__floats2half2_rn(o2, o3));
    } else {
        st.x = h2_as_u32(__floats2half2_rn(acc.x * ni, acc.y * ni));
        st.y = h2_as_u32(__floats2half2_rn(acc.z * ni, acc.w * ni));
    }
    *(uint2*)(hout + (size_t)node * HID + lane * 4) = st;
}

extern "C" void kernel_launch(void* const* d_in, const int* in_sizes, int n_in,
                              void* d_out, int out_size, void* d_ws, size_t ws_size,
                              hipStream_t stream) {
    const float* x0      = (const float*)d_in[0];
    const float* x1      = (const float*)d_in[1];
    const float* x2      = (const float*)d_in[2];
    const float* W_fc0   = (const float*)d_in[3];
    const float* b_fc0   = (const float*)d_in[4];
    const float* W_fc1   = (const float*)d_in[5];
    const float* b_fc1   = (const float*)d_in[6];
    const float* W_fc2   = (const float*)d_in[7];
    const float* b_fc2   = (const float*)d_in[8];
    const float* bias_l0 = (const float*)d_in[9];
    const float* W_l1    = (const float*)d_in[10];
    const float* b_l1    = (const float*)d_in[11];
    const int*   src     = (const int*)d_in[12];
    const int*   dst     = (const int*)d_in[13];

    int n0 = in_sizes[0] / 256;
    int n1 = in_sizes[1] / 128;
    int n2 = in_sizes[2] / 512;
    int N  = n0 + n1 + n2;
    int NE = in_sizes[12];
    int nscan = (N + 1023) / 1024;
    int chunk = (NE + CH - 1) / CH;

    // workspace layout (256B-aligned slices)
    char* w = (char*)d_ws;
    auto alloc = [&](size_t bytes) {
        char* p = w;
        w += (bytes + 255) & ~(size_t)255;
        return p;
    };
    unsigned int* histO = (unsigned int*)alloc((size_t)CH * N * sizeof(int));
    unsigned int* histI = (unsigned int*)alloc((size_t)CH * N * sizeof(int));
    int*      bb       = (int*)alloc((size_t)CH * N * sizeof(int));
    int*      deg_in   = (int*)alloc((size_t)N * sizeof(int));
    float*    norm_out = (float*)alloc((size_t)N * sizeof(float));
    float*    norm_in  = (float*)alloc((size_t)N * sizeof(float));
    int*      row_ptr  = (int*)alloc((size_t)(N + 1) * sizeof(int));
    int*      bsum     = (int*)alloc((size_t)(nscan + 1) * sizeof(int));
    int*      colx     = (int*)alloc((size_t)NE * sizeof(int));
    _Float16* Wt0      = (_Float16*)alloc((size_t)256 * 256 * 2);
    _Float16* Wt1      = (_Float16*)alloc((size_t)128 * 256 * 2);
    _Float16* Wt2      = (_Float16*)alloc((size_t)512 * 256 * 2);
    _Float16* WtL      = (_Float16*)alloc((size_t)256 * 256 * 2);
    __half*   h0h      = (__half*)alloc((size_t)N * HID * sizeof(__half));
    __half*   h1h      = (__half*)alloc((size_t)N * HID * sizeof(__half));
    __half*   aggh     = h0h;   // h0 dead after layer-0 spmm; reuse for layer-1 agg

    // ---- atomic-free CSR build ----
    k_hist<<<CH * 2, 1024, 0, stream>>>(src, histO, NE, N, chunk);
    k_hist<<<CH * 2, 1024, 0, stream>>>(dst, histI, NE, N, chunk);
    k_bbase_norm<<<(N + 255) / 256, 256, 0, stream>>>(histO, histI, bb, deg_in,
                                                      norm_out, norm_in, N);
    k_scan_local<<<nscan, 1024, 0, stream>>>(deg_in, row_ptr, bsum, N);
    k_scan_bsum<<<1, 64, 0, stream>>>(bsum, nscan);
    k_scan_add<<<nscan, 1024, 0, stream>>>(row_ptr, bsum, N, nscan);
    k_place<<<CH * 2, 1024, 0, stream>>>(src, dst, row_ptr, bb, colx, NE, N, chunk);

    // weight convert+transpose to fp16
    k_cvtW<<<256, 256, 0, stream>>>(W_fc0, Wt0, 256);
    k_cvtW<<<256, 128, 0, stream>>>(W_fc1, Wt1, 128);
    k_cvtW<<<256, 512, 0, stream>>>(W_fc2, Wt2, 512);
    k_cvtW<<<256, 256, 0, stream>>>(W_l1,  WtL, 256);

    // per-type linear projections -> fp16 h0, prescaled by norm_out (MFMA)
    k_mgemm<256, 0><<<(n0 + 63) / 64, 256, 0, stream>>>(x0, Wt0, b_fc0, norm_out, h0h, n0, 0);
    k_mgemm<128, 0><<<(n1 + 63) / 64, 256, 0, stream>>>(x1, Wt1, b_fc1, norm_out, h0h, n1, n0);
    k_mgemm<512, 0><<<(n2 + 63) / 64, 256, 0, stream>>>(x2, Wt2, b_fc2, norm_out, h0h, n2, n0 + n1);

    // layer 0: agg + relu + prescale for layer 1 -> fp16 h1
    k_spmm<0><<<(N + 3) / 4, 256, 0, stream>>>(h0h, row_ptr, colx, norm_in, norm_out, bias_l0,
                                               h1h, N);
    // layer 1: agg (with norm_in) -> fp16 agg (aliases h0h)
    k_spmm<1><<<(N + 3) / 4, 256, 0, stream>>>(h1h, row_ptr, colx, norm_in, norm_out, nullptr,
                                               aggh, N);
    // final: relu(agg @ W_l1 + b_l1) -> fp32 d_out (MFMA)
    k_mgemm<256, 1><<<(N + 63) / 64, 256, 0, stream>>>(aggh, WtL, b_l1, nullptr, d_out, N, 0);
}

// Round 10
// 517.189 us; speedup vs baseline: 1.3333x; 1.3333x over previous
//
#include <hip/hip_runtime.h>
#include <hip/hip_fp16.h>

#define HID 256
#define CH 64          // edge chunks for histogram/placement
#define SPLIT 4        // bin quarters per chunk
#define LDSW 6272      // LDS words per bin-quarter (supports nq up to 12544)

typedef _Float16 f16x8 __attribute__((ext_vector_type(8)));
typedef float    f32x4 __attribute__((ext_vector_type(4)));

// ---------- fp16 pack/unpack helpers ----------
__device__ inline unsigned int h2_as_u32(__half2 h) {
    union { __half2 h; unsigned int u; } c; c.h = h; return c.u;
}
__device__ inline float4 u2_to_f4(uint2 u) {
    union { unsigned int u; __half2 h; } a, b;
    a.u = u.x; b.u = u.y;
    float2 fa = __half22float2(a.h);
    float2 fb = __half22float2(b.h);
    return make_float4(fa.x, fa.y, fb.x, fb.y);
}

// ---------------- LDS-privatized histogram (no global atomics) ----------------
// grid = CH*SPLIT blocks: c = bid>>2 (edge chunk), h = bid&3 (bin quarter).
// Packed 16-bit counts in LDS; plain-stores per-(chunk,bin) counts to hist[c*n+bin].
__global__ __launch_bounds__(1024) void k_hist(const int* __restrict__ idx,
                                               unsigned short* __restrict__ hist,
                                               int ne, int n, int chunk) {
    __shared__ unsigned int hl[LDSW];
    int tid = threadIdx.x;
    int c = blockIdx.x >> 2, h = blockIdx.x & 3;
    int nq = (n + SPLIT - 1) / SPLIT;
    int b0 = h * nq;
    int b1 = min(n, b0 + nq);
    int nw = (b1 - b0 + 1) >> 1;
    for (int i = tid; i < nw; i += 1024) hl[i] = 0;
    __syncthreads();
    int e0 = c * chunk, e1 = min(ne, e0 + chunk);
    for (int e = e0 + tid; e < e1; e += 1024) {
        int b = idx[e];
        if (b >= b0 && b < b1) {
            int l = b - b0;
            atomicAdd(&hl[l >> 1], 1u << ((l & 1) << 4));
        }
    }
    __syncthreads();
    for (int i = tid; i < nw; i += 1024) {
        unsigned int v = hl[i];
        int bin = b0 + (i << 1);
        hist[(size_t)c * n + bin] = (unsigned short)(v & 0xFFFFu);
        if (bin + 1 < b1) hist[(size_t)c * n + bin + 1] = (unsigned short)(v >> 16);
    }
}

// ---------------- per-bin: norms + per-chunk placement bases + deg_in ----------------
__global__ void k_bbase_norm(const unsigned short* __restrict__ histO,
                             const unsigned short* __restrict__ histI,
                             unsigned short* __restrict__ bb,
                             int* __restrict__ deg_in,
                             float* __restrict__ norm_out,
                             float* __restrict__ norm_in,
                             int n) {
    int bin = blockIdx.x * 256 + threadIdx.x;
    if (bin >= n) return;
    unsigned int dout = 0;
    #pragma unroll
    for (int c = 0; c < CH; c++) dout += histO[(size_t)c * n + bin];
    unsigned int run = 0;
    #pragma unroll
    for (int c = 0; c < CH; c++) {
        bb[(size_t)c * n + bin] = (unsigned short)run;
        run += histI[(size_t)c * n + bin];
    }
    deg_in[bin] = run;
    norm_out[bin] = dout > 0 ? 1.0f / sqrtf((float)dout) : 1.0f;
    norm_in[bin]  = run  > 0 ? 1.0f / sqrtf((float)run)  : 1.0f;
}

// ---------------- hierarchical exclusive scan: deg_in -> row_ptr ----------------
__global__ void k_scan_local(const int* __restrict__ deg, int* __restrict__ rp,
                             int* __restrict__ bsum, int n) {
    __shared__ int sd[1024];
    int tid = threadIdx.x;
    int i = blockIdx.x * 1024 + tid;
    int v = (i < n) ? deg[i] : 0;
    sd[tid] = v;
    __syncthreads();
    for (int o = 1; o < 1024; o <<= 1) {
        int t = (tid >= o) ? sd[tid - o] : 0;
        __syncthreads();
        sd[tid] += t;
        __syncthreads();
    }
    if (i < n) rp[i] = sd[tid] - v;           // local exclusive
    if (tid == 1023) bsum[blockIdx.x] = sd[1023];
}

__global__ void k_scan_bsum(int* __restrict__ bsum, int nb) {
    if (threadIdx.x == 0 && blockIdx.x == 0) {
        int run = 0;
        for (int i = 0; i < nb; i++) { int v = bsum[i]; bsum[i] = run; run += v; }
        bsum[nb] = run;
    }
}

__global__ void k_scan_add(int* __restrict__ rp, const int* __restrict__ bsum,
                           int n, int nb) {
    int i = blockIdx.x * 1024 + threadIdx.x;
    if (i < n) rp[i] += bsum[blockIdx.x];
    if (i == 0) rp[n] = bsum[nb];
}

// ---------------- place edges into CSR (LDS cursors, no global atomics) ----------------
__global__ __launch_bounds__(1024) void k_place(const int* __restrict__ src,
                                                const int* __restrict__ dst,
                                                const int* __restrict__ rp,
                                                const unsigned short* __restrict__ bb,
                                                int* __restrict__ colx,
                                                int ne, int n, int chunk) {
    __shared__ unsigned int hl[LDSW];
    int tid = threadIdx.x;
    int c = blockIdx.x >> 2, h = blockIdx.x & 3;
    int nq = (n + SPLIT - 1) / SPLIT;
    int b0 = h * nq;
    int b1 = min(n, b0 + nq);
    int nw = (b1 - b0 + 1) >> 1;
    for (int i = tid; i < nw; i += 1024) hl[i] = 0;
    __syncthreads();
    int e0 = c * chunk, e1 = min(ne, e0 + chunk);
    for (int e = e0 + tid; e < e1; e += 1024) {
        int b = dst[e];
        if (b >= b0 && b < b1) {
            int l = b - b0;
            int sh = (l & 1) << 4;
            unsigned int old = atomicAdd(&hl[l >> 1], 1u << sh);
            int pos = (old >> sh) & 0xFFFF;
            colx[rp[b] + bb[(size_t)c * n + b] + pos] = src[e];
        }
    }
}

// ---------------- W convert+transpose: Wt[n][k] = (fp16) W[k][n] ----------------
__global__ void k_cvtW(const float* __restrict__ W, _Float16* __restrict__ Wt, int K) {
    int n = blockIdx.x;
    int k = threadIdx.x;
    Wt[(size_t)n * K + k] = (_Float16)W[(size_t)k * HID + n];
}

// ---------------- MFMA fp16 GEMM: C = epi(A[M,K] @ W[K,256]) ----------------
// block: 64 rows x 256 cols, 256 threads = 4 waves (2x2), BK=64.
// Wt is pre-transposed fp16 [256][K].
// EPI 0: A fp32; C fp16 = (acc + bias[c]) * scale[row0+r]   (per-type linear)
// EPI 1: A fp16; C fp32 = relu(acc + bias[c])               (final layer)
template <int K, int EPI>
__global__ __launch_bounds__(256) void k_mgemm(const void* __restrict__ Av,
                                               const _Float16* __restrict__ Wt,
                                               const float* __restrict__ bias,
                                               const float* __restrict__ scale,
                                               void* __restrict__ Cv,
                                               int M, int row0) {
    __shared__ _Float16 As[64][72];    // 64 rows x BK=64 (+8 pad: 2-way bank alias only)
    __shared__ _Float16 Bs[256][72];   // 256 cols x BK=64 (+8 pad)
    int t = threadIdx.x, lane = t & 63, wave = t >> 6;
    int wm = wave >> 1, wn = wave & 1;          // 2x2 wave grid
    int rbase = blockIdx.x * 64;
    int cl = lane & 15, kg = lane >> 4;         // fragment col / k-group

    f32x4 zero = {0.f, 0.f, 0.f, 0.f};
    f32x4 acc[2][8];
    #pragma unroll
    for (int i = 0; i < 2; i++)
        #pragma unroll
        for (int j = 0; j < 8; j++) acc[i][j] = zero;

    for (int k0 = 0; k0 < K; k0 += 64) {
        // ---- stage A tile (64 x 64), convert fp32->fp16 if EPI==0 ----
        {
            int r = t >> 2, seg = t & 3;           // each thread: 16 halves of one row
            int gr = rbase + r; if (gr >= M) gr = M - 1;
            if (EPI == 0) {
                const float* A = (const float*)Av;
                const float4* p = (const float4*)(A + (size_t)gr * K + k0 + seg * 16);
                float4 a = p[0], b = p[1], c = p[2], d = p[3];
                f16x8 h0 = {(_Float16)a.x, (_Float16)a.y, (_Float16)a.z, (_Float16)a.w,
                            (_Float16)b.x, (_Float16)b.y, (_Float16)b.z, (_Float16)b.w};
                f16x8 h1 = {(_Float16)c.x, (_Float16)c.y, (_Float16)c.z, (_Float16)c.w,
                            (_Float16)d.x, (_Float16)d.y, (_Float16)d.z, (_Float16)d.w};
                *(f16x8*)&As[r][seg * 16]     = h0;
                *(f16x8*)&As[r][seg * 16 + 8] = h1;
            } else {
                const _Float16* A = (const _Float16*)Av;
                const uint4* p = (const uint4*)(A + (size_t)gr * K + k0 + seg * 16);
                *(uint4*)&As[r][seg * 16]     = p[0];
                *(uint4*)&As[r][seg * 16 + 8] = p[1];
            }
        }
        // ---- stage B tile (256 cols x 64 k) from pre-transposed Wt ----
        {
            const uint4* p = (const uint4*)(Wt + (size_t)t * K + k0);
            #pragma unroll
            for (int j = 0; j < 8; j++) *(uint4*)&Bs[t][j * 8] = p[j];
        }
        __syncthreads();

        // ---- MFMA: wave computes 32 x 128 ----
        f16x8 af[2][2];
        #pragma unroll
        for (int mf = 0; mf < 2; mf++)
            #pragma unroll
            for (int c = 0; c < 2; c++)
                af[mf][c] = *(f16x8*)&As[wm * 32 + mf * 16 + cl][c * 32 + kg * 8];
        #pragma unroll
        for (int nf = 0; nf < 8; nf++) {
            int bn = wn * 128 + nf * 16 + cl;
            f16x8 bf0 = *(f16x8*)&Bs[bn][kg * 8];
            f16x8 bf1 = *(f16x8*)&Bs[bn][32 + kg * 8];
            acc[0][nf] = __builtin_amdgcn_mfma_f32_16x16x32_f16(af[0][0], bf0, acc[0][nf], 0, 0, 0);
            acc[0][nf] = __builtin_amdgcn_mfma_f32_16x16x32_f16(af[0][1], bf1, acc[0][nf], 0, 0, 0);
            acc[1][nf] = __builtin_amdgcn_mfma_f32_16x16x32_f16(af[1][0], bf0, acc[1][nf], 0, 0, 0);
            acc[1][nf] = __builtin_amdgcn_mfma_f32_16x16x32_f16(af[1][1], bf1, acc[1][nf], 0, 0, 0);
        }
        __syncthreads();
    }

    // ---- epilogue: C/D layout col=lane&15, row=(lane>>4)*4+reg ----
    #pragma unroll
    for (int mf = 0; mf < 2; mf++) {
        int lr = wm * 32 + mf * 16 + kg * 4;
        int g0 = rbase + lr;
        float s[4];
        if (EPI == 0) {
            #pragma unroll
            for (int r = 0; r < 4; r++) {
                int gr = g0 + r; if (gr >= M) gr = M - 1;
                s[r] = scale[row0 + gr];
            }
        }
        #pragma unroll
        for (int nf = 0; nf < 8; nf++) {
            int col = wn * 128 + nf * 16 + cl;
            float bb = bias[col];
            #pragma unroll
            for (int r = 0; r < 4; r++) {
                int gr = g0 + r;
                if (gr < M) {
                    float v = acc[mf][nf][r] + bb;
                    if (EPI == 0) {
                        ((_Float16*)Cv)[(size_t)(row0 + gr) * HID + col] = (_Float16)(v * s[r]);
                    } else {
                        ((float*)Cv)[(size_t)gr * HID + col] = fmaxf(v, 0.f);
                    }
                }
            }
        }
    }
}

// ---------------- pull-style SpMM over CSR (fp16 rows); 1 wave per dst node; 8x unrolled ----
// MODE 0: hout(fp16) = relu(acc*norm_in + bias) * norm_out  (layer-0 out, prescaled for layer 1)
// MODE 1: hout(fp16) = acc*norm_in                           (pre-GEMM agg for layer 1)
template <int MODE>
__global__ __launch_bounds__(256) void k_spmm(const __half* __restrict__ hin,
                                              const int* __restrict__ rp,
                                              const int* __restrict__ colx,
                                              const float* __restrict__ norm_in,
                                              const float* __restrict__ norm_out,
                                              const float* __restrict__ bias,
                                              __half* __restrict__ hout,
                                              int n) {
    int node = blockIdx.x * 4 + (threadIdx.x >> 6);
    if (node >= n) return;
    int lane = threadIdx.x & 63;
    int start = rp[node], end = rp[node + 1];
    const __half* hb = hin + lane * 4;   // each lane covers feature cols [lane*4, lane*4+4)

    float4 acc = make_float4(0.f, 0.f, 0.f, 0.f);
    float4 acc2 = make_float4(0.f, 0.f, 0.f, 0.f);
    int j = start;
    for (; j + 8 <= end; j += 8) {
        int s0 = colx[j + 0], s1 = colx[j + 1], s2 = colx[j + 2], s3 = colx[j + 3];
        int s4 = colx[j + 4], s5 = colx[j + 5], s6 = colx[j + 6], s7 = colx[j + 7];
        uint2 u0 = *(const uint2*)(hb + (size_t)s0 * HID);
        uint2 u1 = *(const uint2*)(hb + (size_t)s1 * HID);
        uint2 u2 = *(const uint2*)(hb + (size_t)s2 * HID);
        uint2 u3 = *(const uint2*)(hb + (size_t)s3 * HID);
        uint2 u4 = *(const uint2*)(hb + (size_t)s4 * HID);
        uint2 u5 = *(const uint2*)(hb + (size_t)s5 * HID);
        uint2 u6 = *(const uint2*)(hb + (size_t)s6 * HID);
        uint2 u7 = *(const uint2*)(hb + (size_t)s7 * HID);
        float4 v0 = u2_to_f4(u0), v1 = u2_to_f4(u1), v2 = u2_to_f4(u2), v3 = u2_to_f4(u3);
        float4 v4 = u2_to_f4(u4), v5 = u2_to_f4(u5), v6 = u2_to_f4(u6), v7 = u2_to_f4(u7);
        acc.x += v0.x + v1.x; acc.y += v0.y + v1.y; acc.z += v0.z + v1.z; acc.w += v0.w + v1.w;
        acc2.x += v2.x + v3.x; acc2.y += v2.y + v3.y; acc2.z += v2.z + v3.z; acc2.w += v2.w + v3.w;
        acc.x += v4.x + v5.x; acc.y += v4.y + v5.y; acc.z += v4.z + v5.z; acc.w += v4.w + v5.w;
        acc2.x += v6.x + v7.x; acc2.y += v6.y + v7.y; acc2.z += v6.z + v7.z; acc2.w += v6.w + v7.w;
    }
    for (; j < end; j++) {
        int s = colx[j];
        float4 v = u2_to_f4(*(const uint2*)(hb + (size_t)s * HID));
        acc.x += v.x; acc.y += v.y; acc.z += v.z; acc.w += v.w;
    }
    acc.x += acc2.x; acc.y += acc2.y; acc.z += acc2.z; acc.w += acc2.w;

    float ni = norm_in[node];
    uint2 st;
    if (MODE == 0) {
        float no = norm_out[node];
        float4 bb = *(const float4*)(bias + lane * 4);
        float o0 = fmaxf(acc.x * ni + bb.x, 0.f) * no;
        float o1 = fmaxf(acc.y * ni + bb.y, 0.f) * no;
        float o2 = fmaxf(acc.z * ni + bb.z, 0.f) * no;
        float o3 = fmaxf(acc.w * ni + bb.w, 0.f) * no;
        st.x = h2_as_u32(__floats2half2_rn(o0, o1));
        st.y = h2_as_u32(__floats2half2_rn(o2, o3));
    } else {
        st.x = h2_as_u32(__floats2half2_rn(acc.x * ni, acc.y * ni));
        st.y = h2_as_u32(__floats2half2_rn(acc.z * ni, acc.w * ni));
    }
    *(uint2*)(hout + (size_t)node * HID + lane * 4) = st;
}

extern "C" void kernel_launch(void* const* d_in, const int* in_sizes, int n_in,
                              void* d_out, int out_size, void* d_ws, size_t ws_size,
                              hipStream_t stream) {
    const float* x0      = (const float*)d_in[0];
    const float* x1      = (const float*)d_in[1];
    const float* x2      = (const float*)d_in[2];
    const float* W_fc0   = (const float*)d_in[3];
    const float* b_fc0   = (const float*)d_in[4];
    const float* W_fc1   = (const float*)d_in[5];
    const float* b_fc1   = (const float*)d_in[6];
    const float* W_fc2   = (const float*)d_in[7];
    const float* b_fc2   = (const float*)d_in[8];
    const float* bias_l0 = (const float*)d_in[9];
    const float* W_l1    = (const float*)d_in[10];
    const float* b_l1    = (const float*)d_in[11];
    const int*   src     = (const int*)d_in[12];
    const int*   dst     = (const int*)d_in[13];

    int n0 = in_sizes[0] / 256;
    int n1 = in_sizes[1] / 128;
    int n2 = in_sizes[2] / 512;
    int N  = n0 + n1 + n2;
    int NE = in_sizes[12];
    int nscan = (N + 1023) / 1024;
    int chunk = (NE + CH - 1) / CH;

    // workspace layout (256B-aligned slices)
    char* w = (char*)d_ws;
    auto alloc = [&](size_t bytes) {
        char* p = w;
        w += (bytes + 255) & ~(size_t)255;
        return p;
    };
    unsigned short* histO = (unsigned short*)alloc((size_t)CH * N * sizeof(short));
    unsigned short* histI = (unsigned short*)alloc((size_t)CH * N * sizeof(short));
    unsigned short* bb    = (unsigned short*)alloc((size_t)CH * N * sizeof(short));
    int*      deg_in   = (int*)alloc((size_t)N * sizeof(int));
    float*    norm_out = (float*)alloc((size_t)N * sizeof(float));
    float*    norm_in  = (float*)alloc((size_t)N * sizeof(float));
    int*      row_ptr  = (int*)alloc((size_t)(N + 1) * sizeof(int));
    int*      bsum     = (int*)alloc((size_t)(nscan + 1) * sizeof(int));
    int*      colx     = (int*)alloc((size_t)NE * sizeof(int));
    _Float16* Wt0      = (_Float16*)alloc((size_t)256 * 256 * 2);
    _Float16* Wt1      = (_Float16*)alloc((size_t)128 * 256 * 2);
    _Float16* Wt2      = (_Float16*)alloc((size_t)512 * 256 * 2);
    _Float16* WtL      = (_Float16*)alloc((size_t)256 * 256 * 2);
    __half*   h0h      = (__half*)alloc((size_t)N * HID * sizeof(__half));
    __half*   h1h      = (__half*)alloc((size_t)N * HID * sizeof(__half));
    __half*   aggh     = h0h;   // h0 dead after layer-0 spmm; reuse for layer-1 agg

    // ---- atomic-free CSR build (CH*SPLIT = 256 blocks per kernel) ----
    k_hist<<<CH * SPLIT, 1024, 0, stream>>>(src, histO, NE, N, chunk);
    k_hist<<<CH * SPLIT, 1024, 0, stream>>>(dst, histI, NE, N, chunk);
    k_bbase_norm<<<(N + 255) / 256, 256, 0, stream>>>(histO, histI, bb, deg_in,
                                                      norm_out, norm_in, N);
    k_scan_local<<<nscan, 1024, 0, stream>>>(deg_in, row_ptr, bsum, N);
    k_scan_bsum<<<1, 64, 0, stream>>>(bsum, nscan);
    k_scan_add<<<nscan, 1024, 0, stream>>>(row_ptr, bsum, N, nscan);
    k_place<<<CH * SPLIT, 1024, 0, stream>>>(src, dst, row_ptr, bb, colx, NE, N, chunk);

    // weight convert+transpose to fp16
    k_cvtW<<<256, 256, 0, stream>>>(W_fc0, Wt0, 256);
    k_cvtW<<<256, 128, 0, stream>>>(W_fc1, Wt1, 128);
    k_cvtW<<<256, 512, 0, stream>>>(W_fc2, Wt2, 512);
    k_cvtW<<<256, 256, 0, stream>>>(W_l1,  WtL, 256);

    // per-type linear projections -> fp16 h0, prescaled by norm_out (MFMA)
    k_mgemm<256, 0><<<(n0 + 63) / 64, 256, 0, stream>>>(x0, Wt0, b_fc0, norm_out, h0h, n0, 0);
    k_mgemm<128, 0><<<(n1 + 63) / 64, 256, 0, stream>>>(x1, Wt1, b_fc1, norm_out, h0h, n1, n0);
    k_mgemm<512, 0><<<(n2 + 63) / 64, 256, 0, stream>>>(x2, Wt2, b_fc2, norm_out, h0h, n2, n0 + n1);

    // layer 0: agg + relu + prescale for layer 1 -> fp16 h1
    k_spmm<0><<<(N + 3) / 4, 256, 0, stream>>>(h0h, row_ptr, colx, norm_in, norm_out, bias_l0,
                                               h1h, N);
    // layer 1: agg (with norm_in) -> fp16 agg (aliases h0h)
    k_spmm<1><<<(N + 3) / 4, 256, 0, stream>>>(h1h, row_ptr, colx, norm_in, norm_out, nullptr,
                                               aggh, N);
    // final: relu(agg @ W_l1 + b_l1) -> fp32 d_out (MFMA)
    k_mgemm<256, 1><<<(N + 63) / 64, 256, 0, stream>>>(aggh, WtL, b_l1, nullptr, d_out, N, 0);
}